// Round 13
// baseline (281.969 us; speedup 1.0000x reference)
//
#include <hip/hip_runtime.h>
#include <hip/hip_bf16.h>
#include <stdint.h>

// ---------------- problem constants ----------------
#define NB   32
#define NC   256
#define NOC  256
#define HWD  56
#define NPIX 3136      // 56*56 = 14 * 224 exactly
#define PW   58        // padded row width
#define PPIX 3364      // 58*58
#define KTOT 2304      // 9 * 256
#define MOD  512       // fc1 out channels
#define GAPD 16

// workspace layout (bytes)
#define XBT_BYTES ((size_t)NB * PPIX * NC * 2)            // 55,115,776
#define WA_BYTES  ((size_t)NB * NOC * KTOT * 2)           // 37,748,736

typedef __bf16 bf16x8 __attribute__((ext_vector_type(8)));
typedef float  f32x4  __attribute__((ext_vector_type(4)));
typedef unsigned short u16x8 __attribute__((ext_vector_type(8)));

__device__ __forceinline__ unsigned short f2bf(float f) {
    union { float f; unsigned int u; } v; v.f = f;
    unsigned int u = v.u;
    return (unsigned short)((u + 0x7FFFu + ((u >> 16) & 1u)) >> 16);
}

// ---------------- P1: per-batch conv weights, SE fused; K-order = cg*288 + s*32 + cw ----------------
__global__ void wk_kernel(const float* __restrict__ gap,
                          const float* __restrict__ rw, const float* __restrict__ rb,
                          const float* __restrict__ f1w,
                          const float* __restrict__ f2w, const float* __restrict__ f2b,
                          unsigned short* __restrict__ wa) {
    __shared__ float sgap[NB * 257];
    __shared__ float srw[GAPD * 257];
    __shared__ float ssg[NB * GAPD];
    __shared__ float sa[2 * NB];
    __shared__ float sw[KTOT];
    __shared__ float sbv[KTOT];
    int oc = blockIdx.x, c = threadIdx.x;
    #pragma unroll
    for (int i = 0; i < 32; ++i) {
        int idx = i * 256 + c;
        sgap[(idx >> 8) * 257 + (idx & 255)] = gap[idx];
    }
    #pragma unroll
    for (int i = 0; i < 16; ++i) {
        int idx = i * 256 + c;
        srw[(idx >> 8) * 257 + (idx & 255)] = rw[idx];
    }
    const float4* wsrc = (const float4*)(f2w + (size_t)oc * KTOT);
    const float4* bsrc = (const float4*)(f2b + (size_t)oc * KTOT);
    #pragma unroll
    for (int i = 0; i < 3; ++i) {
        int idx = i * 256 + c;
        if (idx < 576) {
            ((float4*)sw)[idx] = wsrc[idx];
            ((float4*)sbv)[idx] = bsrc[idx];
        }
    }
    __syncthreads();
    #pragma unroll
    for (int e = 0; e < 2; ++e) {
        int pair = c * 2 + e;
        int b = pair >> 4, tt = pair & 15;
        float s = rb[tt];
        for (int k = 0; k < NC; ++k) s += sgap[b * 257 + k] * srw[tt * 257 + k];
        ssg[b * GAPD + tt] = s;
    }
    __syncthreads();
    if (c < 64) {
        int b = c >> 1, e = c & 1;
        float s = 0.f;
        #pragma unroll
        for (int tt = 0; tt < GAPD; ++tt)
            s += ssg[b * GAPD + tt] * f1w[(2 * oc + e) * GAPD + tt];
        sa[c] = 1.0f / (1.0f + __expf(-s));
    }
    __syncthreads();
    float w9[9], b9[9];
    #pragma unroll
    for (int s = 0; s < 9; ++s) { w9[s] = sw[c * 9 + s]; b9[s] = sbv[c * 9 + s]; }
    const int hi = (c >= 128);     // rem = c*9+s >= 1152  <=>  c >= 128
    for (int b = 0; b < NB; ++b) {
        float a = hi ? sa[2 * b + 1] : sa[2 * b];
        // NEW k-order: k = (c>>5)*288 + s*32 + (c&31)
        unsigned short* dst = wa + (size_t)(b * NOC + oc) * KTOT + (c >> 5) * 288 + (c & 31);
        #pragma unroll
        for (int s = 0; s < 9; ++s)
            dst[s * 32] = f2bf(a * w9[s] + b9[s]);
    }
}

// ---------------- P2: x -> bf16 NHWC, halo fused, shuffle-reduced GAP ----------------
#define TSTR 59
__global__ void xpose_kernel(const float* __restrict__ x, unsigned short* __restrict__ xbt,
                             float* __restrict__ gap) {
    __shared__ unsigned short tile[NC * TSTR];
    int py = blockIdx.x, b = blockIdx.y, t = threadIdx.x;
    int wv = t >> 6, l = t & 63;
    const u16x8 z = {};
    unsigned short* xb = xbt + (size_t)b * PPIX * NC;
    if (t < 64)
        *(u16x8*)(xb + ((size_t)(1 + py) * PW + ((t >= 32) ? 57 : 0)) * NC + (t & 31) * 8) = z;
    if (py == 0)
        for (int i = t; i < 1856; i += 256)
            *(u16x8*)(xb + (size_t)(i >> 5) * NC + (i & 31) * 8) = z;
    if (py == 55)
        for (int i = t; i < 1856; i += 256)
            *(u16x8*)(xb + (size_t)(57 * PW + (i >> 5)) * NC + (i & 31) * 8) = z;

    const float* xs = x + (size_t)b * NC * NPIX + py * HWD;
    int q = l & 15;
    int rb4 = l >> 4;
    #pragma unroll
    for (int it = 0; it < 16; ++it) {
        int c = wv * 64 + it * 4 + rb4;
        float4 v = {0.f, 0.f, 0.f, 0.f};
        if (q < 14) {
            v = *(const float4*)(xs + (size_t)c * NPIX + q * 4);
            unsigned short* tr = tile + c * TSTR + q * 4;
            tr[0] = f2bf(v.x); tr[1] = f2bf(v.y); tr[2] = f2bf(v.z); tr[3] = f2bf(v.w);
        }
        float s4 = v.x + v.y + v.z + v.w;
        s4 += __shfl_xor(s4, 1);
        s4 += __shfl_xor(s4, 2);
        s4 += __shfl_xor(s4, 4);
        s4 += __shfl_xor(s4, 8);
        if (q == 0) atomicAdd(&gap[b * NC + c], s4 * (1.0f / NPIX));
    }
    __syncthreads();
    int cch = t & 31, pg = t >> 5;
    for (int i = 0; i < 7; ++i) {
        int px = pg * 7 + i;
        u16x8 v;
        #pragma unroll
        for (int j = 0; j < 8; ++j) v[j] = tile[(cch * 8 + j) * TSTR + px];
        *(u16x8*)(xb + ((size_t)(1 + py) * PW + 1 + px) * NC + cch * 8) = v;
    }
}

// ---------------- main GEMM: 256oc x 224px, 8 waves (4Mx2N, wave 64x112), strip-B ----------------
// K-order: cg (8 x 32ch) outer, shift s inner -> per cg stage ONE 6-row pixel strip
// (384 sp x 32ch = 24KB) read by all 9 shifts at offset dy*58+dx. A: R10-proven ring-4
// (slice 16KB, unit swizzle, 0 conflicts), issue-ahead-2 pre-wait. Strip: triple-buffer,
// issued post-barrier at s0 for cg+2 (WAR-safe). Per-step vmcnt desk-simulated:
// [4,7,7,4,4,4,4,4,4] on strip cg's (0..5), all-4 on cg 6/7, drain 2/0.
#define A_SLOT   16384
#define STRIP_OFF 65536
#define STRIP_SZ  24576

#define PWAIT_(N) do { asm volatile("s_waitcnt vmcnt(" #N ")" ::: "memory"); \
    __builtin_amdgcn_s_barrier(); __builtin_amdgcn_sched_barrier(0); } while (0)
#define PWAIT(N) PWAIT_(N)

__global__ __launch_bounds__(512, 2) void conv_gemm(
    const unsigned short* __restrict__ wa,   // [32][256][2304] bf16 (k = cg*288+s*32+cw)
    const unsigned short* __restrict__ xbt,  // [32][3364][256] bf16 (padded NHWC)
    float* __restrict__ out)                 // [32][256][3136]
{
    __shared__ __attribute__((aligned(16))) char lds[STRIP_OFF + 3 * STRIP_SZ];  // 139264 B

    // XCD swizzle: 448 blocks = 8 XCD * 56; 4 whole batches per XCD
    const int bid = blockIdx.x;
    const int wg  = (bid & 7) * 56 + (bid >> 3);
    const int b   = wg / 14, nt = wg % 14;

    const int t = threadIdx.x;
    const int w = t >> 6, l = t & 63;            // 8 waves
    const int wm = w >> 1, wn = w & 1;           // 4M x 2N, wave tile 64oc x 112px

    const unsigned short* waB = wa + (size_t)b * NOC * KTOT;
    const unsigned short* xbB = xbt + (size_t)b * PPIX * NC;
    const int py0 = nt * 4;                      // strip base = padded row py0

    // ---- A staging sources (R10-proven unit swizzle) ----
    const unsigned short* srcA[2];
    #pragma unroll
    for (int j = 0; j < 2; ++j) {
        int cix = j * 512 + t;
        int cc  = cix & 63;
        int row = (cix >> 6) * 16 + (cc >> 2);
        int qv  = (cc & 3) ^ ((cc >> 3) & 3);
        srcA[j] = waB + (size_t)row * KTOT + qv * 8;
    }
    // ---- strip staging sources: granule g = j*512+t -> sp = g>>2, phys = g&3,
    //      stored logical kq = (phys - (sp>>1)) & 3  [read swizzle inverse]
    const unsigned short* srcS[3];
    #pragma unroll
    for (int j = 0; j < 3; ++j) {
        int g = j * 512 + t;
        int sp = g >> 2; if (sp > 347) sp = 347;   // pad granules: clamp, never read
        int kq = ((g & 3) - (sp >> 1)) & 3;
        srcS[j] = xbB + (size_t)(py0 * 58 + sp) * NC + kq * 8;
    }
    const int t16 = t * 16;

    auto stageA = [&](int tp, int slot) {
        char* sb = lds + slot * A_SLOT;
        #pragma unroll
        for (int j = 0; j < 2; ++j)
            __builtin_amdgcn_global_load_lds(
                (const __attribute__((address_space(1))) void*)(srcA[j] + tp * 32),
                (__attribute__((address_space(3))) void*)(sb + j * 8192 + t16), 16, 0, 0);
    };
    auto stageS = [&](int cg, int buf) {
        char* sb = lds + STRIP_OFF + buf * STRIP_SZ;
        #pragma unroll
        for (int j = 0; j < 3; ++j)
            __builtin_amdgcn_global_load_lds(
                (const __attribute__((address_space(1))) void*)(srcS[j] + cg * 32),
                (__attribute__((address_space(3))) void*)(sb + j * 8192 + t16), 16, 0, 0);
    };

    // ---- read-side lane constants ----
    const int physq16 = (((l >> 4) ^ ((l >> 1) & 3)) << 4);   // A (R10-proven)
    const int arow = (l & 15) << 6;
    const int kq = l >> 4;                                     // B k-quarter
    int rs[7];
    #pragma unroll
    for (int j = 0; j < 7; ++j) {
        int prow = wn * 112 + j * 16 + (l & 15);
        rs[j] = prow + 2 * (prow / 56);
    }

    f32x4 acc[4][7] = {};

    auto compute = [&](int aslot, int buf, int sh) {
        const char* ab = lds + aslot * A_SLOT;
        const char* sb = lds + STRIP_OFF + buf * STRIP_SZ;
        bf16x8 af[4], bfr[7];
        #pragma unroll
        for (int m = 0; m < 4; ++m)
            af[m] = *(const bf16x8*)(ab + (wm * 4 + m) * 1024 + arow + physq16);
        #pragma unroll
        for (int j = 0; j < 7; ++j) {
            int sp = rs[j] + sh;
            bfr[j] = *(const bf16x8*)(sb + sp * 64 + (((kq + (sp >> 1)) & 3) << 4));
        }
        __builtin_amdgcn_s_setprio(1);
        #pragma unroll
        for (int m = 0; m < 4; ++m)
            #pragma unroll
            for (int j = 0; j < 7; ++j)
                acc[m][j] = __builtin_amdgcn_mfma_f32_16x16x32_bf16(af[m], bfr[j], acc[m][j], 0, 0, 0);
        __builtin_amdgcn_s_setprio(0);
    };

#define STEP(P, VM, DOSTRIP, CG, SH)                      \
    do {                                                  \
        if ((P) + 2 < 72) stageA((P) + 2, ((P) + 2) & 3); \
        PWAIT(VM);                                        \
        if (DOSTRIP) stageS((CG) + 2, ((CG) + 2) % 3);    \
        compute((P) & 3, (CG) % 3, SH);                   \
    } while (0)

    // prologue: strips for cg0,cg1; A slices 0,1
    stageS(0, 0); stageS(1, 1); stageA(0, 0); stageA(1, 1);

    #pragma unroll 1
    for (int cg = 0; cg < 6; ++cg) {
        const int p0 = cg * 9;
        STEP(p0 + 0, 4, 1, cg, 0);
        STEP(p0 + 1, 7, 0, cg, 1);
        STEP(p0 + 2, 7, 0, cg, 2);
        STEP(p0 + 3, 4, 0, cg, 58);
        STEP(p0 + 4, 4, 0, cg, 59);
        STEP(p0 + 5, 4, 0, cg, 60);
        STEP(p0 + 6, 4, 0, cg, 116);
        STEP(p0 + 7, 4, 0, cg, 117);
        STEP(p0 + 8, 4, 0, cg, 118);
    }
    // cg = 6 (no strip issues)
    STEP(54, 4, 0, 6, 0);   STEP(55, 4, 0, 6, 1);   STEP(56, 4, 0, 6, 2);
    STEP(57, 4, 0, 6, 58);  STEP(58, 4, 0, 6, 59);  STEP(59, 4, 0, 6, 60);
    STEP(60, 4, 0, 6, 116); STEP(61, 4, 0, 6, 117); STEP(62, 4, 0, 6, 118);
    // cg = 7 (drain tail)
    STEP(63, 4, 0, 7, 0);   STEP(64, 4, 0, 7, 1);   STEP(65, 4, 0, 7, 2);
    STEP(66, 4, 0, 7, 58);  STEP(67, 4, 0, 7, 59);  STEP(68, 4, 0, 7, 60);
    STEP(69, 4, 0, 7, 116); STEP(70, 2, 0, 7, 117); STEP(71, 0, 0, 7, 118);
#undef STEP

    // epilogue: D lane map col = l&15 (pixel), row = (l>>4)*4 + r (oc)
    const int ocb = wm * 64 + ((l >> 4) << 2);
    const int pxb = nt * 224 + wn * 112 + (l & 15);
    #pragma unroll
    for (int i = 0; i < 4; ++i) {
        #pragma unroll
        for (int j = 0; j < 7; ++j) {
            float* o = out + ((size_t)(b * NOC + ocb + i * 16)) * NPIX + pxb + j * 16;
            o[0]        = acc[i][j][0];
            o[NPIX]     = acc[i][j][1];
            o[2 * NPIX] = acc[i][j][2];
            o[3 * NPIX] = acc[i][j][3];
        }
    }
}

extern "C" void kernel_launch(void* const* d_in, const int* in_sizes, int n_in,
                              void* d_out, int out_size, void* d_ws, size_t ws_size,
                              hipStream_t stream) {
    (void)in_sizes; (void)n_in; (void)out_size; (void)ws_size;
    const float* x   = (const float*)d_in[0];
    const float* rw  = (const float*)d_in[1];
    const float* rb  = (const float*)d_in[2];
    const float* f1w = (const float*)d_in[3];
    const float* f2w = (const float*)d_in[4];
    const float* f2b = (const float*)d_in[5];
    float* out = (float*)d_out;

    char* wsb = (char*)d_ws;
    unsigned short* xbt = (unsigned short*)wsb;
    unsigned short* wa  = (unsigned short*)(wsb + XBT_BYTES);
    float* gap = (float*)(wsb + XBT_BYTES + WA_BYTES);

    hipMemsetAsync(gap, 0, (size_t)NB * NC * 4, stream);
    xpose_kernel<<<dim3(56, 32), 256, 0, stream>>>(x, xbt, gap);
    wk_kernel<<<dim3(256), 256, 0, stream>>>(gap, rw, rb, f1w, f2w, f2b, wa);
    conv_gemm<<<dim3(448), 512, 0, stream>>>(wa, xbt, out);
}